// Round 10
// baseline (363.856 us; speedup 1.0000x reference)
//
#include <hip/hip_runtime.h>
#include <hip/hip_bf16.h>

// B=1024, S=128, E=256, H=2, DH=128.  v/Wv/bv dead in the reference.
// out = softmax((q@Wq+bq)/16 |h . (k@Wk+bk)|h + (mask==0)) @ Wo + bo
//
// R10 hybrid (all pieces from passing kernels):
//  R2 front end: burst-stage k->LDS (16 float4/thread), kp GEMM A from LDS;
//  R8 back end: qp in registers (D->B k-slot chain), transposed GEMM2
//  (uint2 P stores), transposed GEMM3 (float4 out stores).
// 128KB LDS: stA (k -> q -> P) + kpT.  512 thr, (512,2) => 128 VGPR cap.
#define NB 1024
#define NS 128
#define NE 256

typedef __attribute__((ext_vector_type(8))) short bf16x8;
typedef __attribute__((ext_vector_type(4))) float f32x4;

union BF8 { bf16x8 v; unsigned u[4]; unsigned short s[8]; };

__device__ __forceinline__ unsigned short f2bf(float x) {
  unsigned u = __float_as_uint(x);
  u = (u + 0x7fffu + ((u >> 16) & 1u)) >> 16;   // RNE
  return (unsigned short)u;
}

__device__ __forceinline__ unsigned packbf(float lo, float hi) {
  return (unsigned)f2bf(lo) | ((unsigned)f2bf(hi) << 16);
}

__device__ __forceinline__ f32x4 MF(bf16x8 a, bf16x8 b, f32x4 c) {
  return __builtin_amdgcn_mfma_f32_16x16x32_bf16(a, b, c, 0, 0, 0);
}

// WT[n][k] = W[k][n] bf16; Wq prescaled by 1/16.
__global__ void prep_weights(const float* __restrict__ Wq,
                             const float* __restrict__ Wk,
                             const float* __restrict__ Wo,
                             short* __restrict__ WqT,
                             short* __restrict__ WkT,
                             short* __restrict__ WoT) {
  int idx = blockIdx.x * blockDim.x + threadIdx.x;  // = n*256 + k
  int n = idx >> 8;
  int kk = idx & 255;
  WqT[idx] = (short)f2bf(Wq[kk * NE + n] * 0.0625f);
  WkT[idx] = (short)f2bf(Wk[kk * NE + n]);
  WoT[idx] = (short)f2bf(Wo[kk * NE + n]);
}

// Burst-stage 128x256 f32 -> LDS bf16, 512B rows, XOR swizzle (R2-proven).
__device__ __forceinline__ void stage_tile(const float* __restrict__ src,
                                           char* __restrict__ dst, int t) {
  #pragma unroll
  for (int i = 0; i < 16; ++i) {
    int idx = t + i * 512;                       // coalesced float4
    float4 v = reinterpret_cast<const float4*>(src)[idx];
    int row = idx >> 6;
    int colb = (idx & 63) << 3;
    ushort4 u;
    u.x = f2bf(v.x); u.y = f2bf(v.y); u.z = f2bf(v.z); u.w = f2bf(v.w);
    *reinterpret_cast<ushort4*>(dst + row * 512 + (colb ^ ((row & 7) << 4))) = u;
  }
}

__global__ __launch_bounds__(512, 2)
void fused_attn5(const float* __restrict__ q,
                 const float* __restrict__ kin,
                 const int* __restrict__ am,
                 const short* __restrict__ WqT,
                 const short* __restrict__ WkT,
                 const short* __restrict__ WoT,
                 const float* __restrict__ bq,
                 const float* __restrict__ bk,
                 const float* __restrict__ bo,
                 float* __restrict__ out) {
  extern __shared__ char LDS[];
  char* stA = LDS;           // 64KB: staged k -> staged q -> P[s][j]
  char* kpT = LDS + 65536;   // 64KB: kpT[e][m], 256 rows x 256B, swizzled

  const int t = threadIdx.x;
  const int lane = t & 63;
  const int wid = t >> 6;        // 8 waves
  const int cl = lane & 15;
  const int c4 = lane >> 4;
  const int b = blockIdx.x;
  const float* qb = q + (size_t)b * (NS * NE);
  const float* kb = kin + (size_t)b * (NS * NE);

  // ---- P1: stage k -> stA ----
  stage_tile(kb, stA, t);
  __syncthreads();

  // ---- P2: kp = k @ Wk + bk -> kpT[e][m]  (wave: eg=wid>>2, mg=wid&3) ----
  {
    const int eg = wid >> 2;     // e-half (128 wide)
    const int mg = wid & 3;      // m-band (32 wide)
    f32x4 acc[2][8];             // [mt][et]
    #pragma unroll
    for (int mt = 0; mt < 2; ++mt)
      #pragma unroll
      for (int et = 0; et < 8; ++et) acc[mt][et] = (f32x4){0.f, 0.f, 0.f, 0.f};
    #pragma unroll
    for (int ks = 0; ks < 8; ++ks) {
      const int kel = ks * 32 + c4 * 8;
      bf16x8 a[2];
      #pragma unroll
      for (int mt = 0; mt < 2; ++mt) {
        int mrow = mg * 32 + mt * 16 + cl;
        a[mt] = *reinterpret_cast<const bf16x8*>(
            stA + mrow * 512 + ((kel * 2) ^ ((mrow & 7) << 4)));
      }
      #pragma unroll
      for (int et = 0; et < 8; ++et) {
        bf16x8 bb = *reinterpret_cast<const bf16x8*>(
            WkT + (eg * 128 + et * 16 + cl) * 256 + kel);
        #pragma unroll
        for (int mt = 0; mt < 2; ++mt)
          acc[mt][et] = MF(a[mt], bb, acc[mt][et]);
      }
    }
    // D: col=cl -> e, rows (c4*4+r) -> m.  ushort4 packs 4 consecutive m.
    #pragma unroll
    for (int et = 0; et < 8; ++et) {
      int e = eg * 128 + et * 16 + cl;
      float bkv = bk[e];
      #pragma unroll
      for (int mt = 0; mt < 2; ++mt) {
        int m0 = mg * 32 + mt * 16 + c4 * 4;
        ushort4 u;
        u.x = f2bf(acc[mt][et][0] + bkv);
        u.y = f2bf(acc[mt][et][1] + bkv);
        u.z = f2bf(acc[mt][et][2] + bkv);
        u.w = f2bf(acc[mt][et][3] + bkv);
        *reinterpret_cast<ushort4*>(
            kpT + e * 256 + ((m0 * 2) ^ ((e & 7) << 4))) = u;
      }
    }
  }
  __syncthreads();   // kp reads of stA done; kpT fully written

  // ---- P3: stage q -> stA (overwrite) ----
  stage_tile(qb, stA, t);
  __syncthreads();

  // ---- P4: qp^T in registers (transposed GEMM; wave: h=wid>>2, sb=wid&3) --
  const int h = wid >> 2;        // head (0..1)
  const int sb = wid & 3;        // s-band (32 wide)
  unsigned qpk[8][2][2];         // [et(=ks)][st][pair]
  {
    f32x4 acc[8][2];             // [et][ct]
    #pragma unroll
    for (int et = 0; et < 8; ++et)
      #pragma unroll
      for (int ct = 0; ct < 2; ++ct) acc[et][ct] = (f32x4){0.f, 0.f, 0.f, 0.f};
    #pragma unroll
    for (int ks = 0; ks < 8; ++ks) {
      const int kel = ks * 32 + c4 * 8;
      bf16x8 bb[2];
      #pragma unroll
      for (int ct = 0; ct < 2; ++ct) {
        int srow = sb * 32 + ct * 16 + cl;
        bb[ct] = *reinterpret_cast<const bf16x8*>(
            stA + srow * 512 + ((kel * 2) ^ ((srow & 7) << 4)));
      }
      #pragma unroll
      for (int eh = 0; eh < 2; ++eh) {
        bf16x8 a[4];
        #pragma unroll
        for (int e4 = 0; e4 < 4; ++e4)
          a[e4] = *reinterpret_cast<const bf16x8*>(
              WqT + (h * 128 + (eh * 4 + e4) * 16 + cl) * 256 + kel);
        #pragma unroll
        for (int e4 = 0; e4 < 4; ++e4)
          #pragma unroll
          for (int ct = 0; ct < 2; ++ct)
            acc[eh * 4 + e4][ct] = MF(a[e4], bb[ct], acc[eh * 4 + e4][ct]);
      }
    }
    #pragma unroll
    for (int et = 0; et < 8; ++et) {
      int e0 = h * 128 + et * 16 + c4 * 4;
      float4 bq4 = *reinterpret_cast<const float4*>(bq + e0);
      #pragma unroll
      for (int st = 0; st < 2; ++st) {
        qpk[et][st][0] = packbf(acc[et][st][0] + bq4.x * 0.0625f,
                                acc[et][st][1] + bq4.y * 0.0625f);
        qpk[et][st][1] = packbf(acc[et][st][2] + bq4.z * 0.0625f,
                                acc[et][st][3] + bq4.w * 0.0625f);
      }
    }
  }
  __syncthreads();   // q reads of stA done -> stA free for P

  // ---- P5: GEMM2 (K=16 chain) + mask + softmax + P-write (R8-proven) ----
  #pragma unroll
  for (int st = 0; st < 2; ++st) {
    f32x4 sacc[8];
    #pragma unroll
    for (int jt = 0; jt < 8; ++jt) sacc[jt] = (f32x4){0.f, 0.f, 0.f, 0.f};
    #pragma unroll
    for (int ks = 0; ks < 8; ++ks) {
      BF8 bb;
      bb.u[0] = qpk[ks][st][0]; bb.u[1] = qpk[ks][st][1];
      bb.u[2] = 0; bb.u[3] = 0;
      #pragma unroll
      for (int jh = 0; jh < 2; ++jh) {
        BF8 a[4];
        #pragma unroll
        for (int j4 = 0; j4 < 4; ++j4) {
          int jt = jh * 4 + j4;
          uint2 d = *reinterpret_cast<const uint2*>(
              kpT + (h * 128 + jt * 16 + cl) * 256 +
              ((ks * 32 + c4 * 8) ^ ((cl & 7) << 4)));
          a[j4].u[0] = d.x; a[j4].u[1] = d.y; a[j4].u[2] = 0; a[j4].u[3] = 0;
        }
        #pragma unroll
        for (int j4 = 0; j4 < 4; ++j4)
          sacc[jh * 4 + j4] = MF(a[j4].v, bb.v, sacc[jh * 4 + j4]);
      }
    }
    // additive mask: +1.0 where attention_mask[b][j]==0 (j = head-dim axis)
    #pragma unroll
    for (int jt = 0; jt < 8; ++jt) {
      int4 mv = *reinterpret_cast<const int4*>(am + b * NS + jt * 16 + c4 * 4);
      sacc[jt][0] += (mv.x == 0) ? 1.f : 0.f;
      sacc[jt][1] += (mv.y == 0) ? 1.f : 0.f;
      sacc[jt][2] += (mv.z == 0) ? 1.f : 0.f;
      sacc[jt][3] += (mv.w == 0) ? 1.f : 0.f;
    }
    // softmax along j: 32 in-lane, then xor 16/32 across c4 groups
    float mx = -1e30f;
    #pragma unroll
    for (int jt = 0; jt < 8; ++jt)
      #pragma unroll
      for (int r = 0; r < 4; ++r) mx = fmaxf(mx, sacc[jt][r]);
    mx = fmaxf(mx, __shfl_xor(mx, 16, 64));
    mx = fmaxf(mx, __shfl_xor(mx, 32, 64));
    float sum = 0.f;
    #pragma unroll
    for (int jt = 0; jt < 8; ++jt)
      #pragma unroll
      for (int r = 0; r < 4; ++r) {
        float ev = __expf(sacc[jt][r] - mx);
        sacc[jt][r] = ev;
        sum += ev;
      }
    sum += __shfl_xor(sum, 16, 64);
    sum += __shfl_xor(sum, 32, 64);
    float rinv = 1.0f / sum;
    // P[s][j] -> stA (disjoint from kpT; no barrier needed inside P5)
    int s = sb * 32 + st * 16 + cl;
    #pragma unroll
    for (int jt = 0; jt < 8; ++jt) {
      uint2 w;
      w.x = packbf(sacc[jt][0] * rinv, sacc[jt][1] * rinv);
      w.y = packbf(sacc[jt][2] * rinv, sacc[jt][3] * rinv);
      *reinterpret_cast<uint2*>(
          stA + s * 512 + ((h * 256 + jt * 32 + c4 * 8) ^ ((s & 7) << 4))) = w;
    }
  }
  __syncthreads();

  // ---- P6: GEMM3 (transposed): out[s][e] = sum_j Wo[j][e]*P[s][j] + bo ----
  float* ob = out + (size_t)b * (NS * NE);
  #pragma unroll
  for (int eti = 0; eti < 2; ++eti) {
    const int et = wid * 2 + eti;               // 16 e-tiles over 8 waves
    bf16x8 a[8];
    #pragma unroll
    for (int ks = 0; ks < 8; ++ks)
      a[ks] = *reinterpret_cast<const bf16x8*>(
          WoT + (et * 16 + cl) * NE + ks * 32 + c4 * 8);
    float4 bo4 = *reinterpret_cast<const float4*>(bo + et * 16 + c4 * 4);
    #pragma unroll
    for (int su = 0; su < 8; ++su) {
      f32x4 acc = (f32x4){0.f, 0.f, 0.f, 0.f};
      const int row = su * 16 + cl;
      #pragma unroll
      for (int ks = 0; ks < 8; ++ks) {
        bf16x8 bv = *reinterpret_cast<const bf16x8*>(
            stA + row * 512 + ((ks * 64 + c4 * 16) ^ ((row & 7) << 4)));
        acc = MF(a[ks], bv, acc);
      }
      float4 o;
      o.x = acc[0] + bo4.x;
      o.y = acc[1] + bo4.y;
      o.z = acc[2] + bo4.z;
      o.w = acc[3] + bo4.w;
      *reinterpret_cast<float4*>(ob + row * NE + et * 16 + c4 * 4) = o;
    }
  }
}

extern "C" void kernel_launch(void* const* d_in, const int* in_sizes, int n_in,
                              void* d_out, int out_size, void* d_ws, size_t ws_size,
                              hipStream_t stream) {
  const float* q  = (const float*)d_in[0];
  const float* k  = (const float*)d_in[1];
  // d_in[2] = v : dead in the reference, never touched
  const int*   am = (const int*)d_in[3];
  const float* Wq = (const float*)d_in[4];
  const float* bq = (const float*)d_in[5];
  const float* Wk = (const float*)d_in[6];
  const float* bk = (const float*)d_in[7];
  // d_in[8] = Wv, d_in[9] = bv : dead
  const float* Wo = (const float*)d_in[10];
  const float* bo = (const float*)d_in[11];
  float* out = (float*)d_out;

  // workspace: 3 x 256x256 bf16 transposed weights = 384KB
  short* WqT = (short*)d_ws;
  short* WkT = WqT + NE * NE;
  short* WoT = WkT + NE * NE;

  prep_weights<<<NE * NE / 256, 256, 0, stream>>>(Wq, Wk, Wo, WqT, WkT, WoT);

  (void)hipFuncSetAttribute((const void*)fused_attn5,
                            hipFuncAttributeMaxDynamicSharedMemorySize, 131072);
  fused_attn5<<<NB, 512, 131072, stream>>>(q, k, am, WqT, WkT, WoT,
                                           bq, bk, bo, out);
}